// Round 9
// baseline (534.195 us; speedup 1.0000x reference)
//
#include <hip/hip_runtime.h>
#include <stdint.h>

typedef __attribute__((ext_vector_type(4))) float f32x4;
typedef __attribute__((ext_vector_type(8))) short s16x8;

// ---------- bf16 helpers ----------
__device__ __forceinline__ unsigned short bf16_rne(float f) {
    union { float f; unsigned u; } v; v.f = f;
    return (unsigned short)((v.u + 0x7fffu + ((v.u >> 16) & 1u)) >> 16);
}
__device__ __forceinline__ float bf16_to_f32(unsigned short h) {
    union { unsigned u; float f; } v; v.u = ((unsigned)h) << 16;
    return v.f;
}

// async global->LDS 16B per lane. LDS dest must be wave-uniform base (+lane*16).
__device__ __forceinline__ void async_copy16(unsigned short* lds, const unsigned short* glb) {
    __builtin_amdgcn_global_load_lds(
        (const __attribute__((address_space(1))) unsigned int*)(glb),
        (__attribute__((address_space(3))) unsigned int*)(lds),
        16, 0, 0);
}

// Problem dims: B=16, C=256, CI=128, H=W=64, N=4096, NP=1024 (pooled 32x32)

// ---------------------------------------------------------------------------
// wsplit: pre-split conv weights to bf16 hi/lo planes; W_w to single bf16.
// wH/wL layout: [0..32767]=theta, [32768..65535]=phi, [65536..98303]=g.
// grid 512 x 256 thr = 131072 = 98304 + 32768 (wbf).
// ---------------------------------------------------------------------------
__global__ __launch_bounds__(256) void wsplit_kernel(
    const float* __restrict__ th_w, const float* __restrict__ ph_w,
    const float* __restrict__ g_w,  const float* __restrict__ W_w,
    unsigned short* __restrict__ wH, unsigned short* __restrict__ wL,
    unsigned short* __restrict__ wbf)
{
    int idx = blockIdx.x * 256 + threadIdx.x;
    if (idx < 98304) {
        const float* src = (idx < 32768) ? th_w : ((idx < 65536) ? ph_w : g_w);
        float v = src[idx & 32767];
        unsigned short h = bf16_rne(v);
        wH[idx] = h;
        wL[idx] = bf16_rne(v - bf16_to_f32(h));
    } else {
        int off = idx - 98304;
        wbf[off] = bf16_rne(W_w[off]);
    }
}

// ---------------------------------------------------------------------------
// xsplit: x [16][256][4096] f32 -> xtH/xtL [16][4096][256] bf16 (transposed
// hi/lo split), via LDS tile transpose (pad 36 shorts = 72B rows).
// ---------------------------------------------------------------------------
__global__ __launch_bounds__(256) void xsplit_kernel(
    const float* __restrict__ x,
    unsigned short* __restrict__ xtH, unsigned short* __restrict__ xtL)
{
    const int b   = blockIdx.y;
    const int n0  = blockIdx.x * 128;
    const int tid = threadIdx.x;
    __shared__ unsigned short Th[128][36];
    __shared__ unsigned short Tl[128][36];
    const int row  = tid >> 1;
    const int half = tid & 1;

    for (int kc = 0; kc < 256; kc += 32) {
        __syncthreads();
#pragma unroll
        for (int i = 0; i < 16; i++) {
            int lin = i * 256 + tid;
            int cc = lin >> 7, nn = lin & 127;
            float v = x[((size_t)b * 256 + kc + cc) * 4096 + n0 + nn];
            unsigned short h = bf16_rne(v);
            Th[nn][cc] = h;
            Tl[nn][cc] = bf16_rne(v - bf16_to_f32(h));
        }
        __syncthreads();
        // thread -> 16 shorts of row `row`, cols [half*16, half*16+16)
        uint2 a0 = *(const uint2*)&Th[row][half * 16 + 0];
        uint2 a1 = *(const uint2*)&Th[row][half * 16 + 4];
        uint2 a2 = *(const uint2*)&Th[row][half * 16 + 8];
        uint2 a3 = *(const uint2*)&Th[row][half * 16 + 12];
        uint2 b0 = *(const uint2*)&Tl[row][half * 16 + 0];
        uint2 b1 = *(const uint2*)&Tl[row][half * 16 + 4];
        uint2 b2 = *(const uint2*)&Tl[row][half * 16 + 8];
        uint2 b3 = *(const uint2*)&Tl[row][half * 16 + 12];
        size_t dst = ((size_t)b * 4096 + n0 + row) * 256 + kc + half * 16;
        uint4 h0; h0.x = a0.x; h0.y = a0.y; h0.z = a1.x; h0.w = a1.y;
        uint4 h1; h1.x = a2.x; h1.y = a2.y; h1.z = a3.x; h1.w = a3.y;
        uint4 l0; l0.x = b0.x; l0.y = b0.y; l0.z = b1.x; l0.w = b1.y;
        uint4 l1; l1.x = b2.x; l1.y = b2.y; l1.z = b3.x; l1.w = b3.y;
        *(uint4*)(xtH + dst)     = h0;
        *(uint4*)(xtH + dst + 8) = h1;
        *(uint4*)(xtL + dst)     = l0;
        *(uint4*)(xtL + dst + 8) = l1;
    }
}

// ---------------------------------------------------------------------------
// conv1x1 v2: LDS-free, barrier-free. A-frags read directly from pre-split
// transposed xt (b128, L1-resident tile reuse across waves); weights from
// pre-split planes (b128, zero VALU). MODE 0: theta (no pool, split out
// [b][n][o]); MODE 1: phi (pool, split out [b][m][o]); MODE 2: g (pool,
// single, out [b][o][m], hi-term only).
// ---------------------------------------------------------------------------
template<int MODE>
__global__ __launch_bounds__(256, 4) void conv_kernel(
    const unsigned short* __restrict__ xtH,  // [16][4096][256]
    const unsigned short* __restrict__ xtL,
    const unsigned short* __restrict__ wHs,  // [128][256] section
    const unsigned short* __restrict__ wLs,
    const float* __restrict__ bias,
    unsigned short* __restrict__ outH,
    unsigned short* __restrict__ outL)
{
    const int b   = blockIdx.y;
    const int n0  = blockIdx.x * 128;
    const int tid = threadIdx.x;
    const int wv  = tid >> 6;
    const int l   = tid & 63;
    const int lg  = l >> 4;
    const int lc  = l & 15;

    f32x4 acc[8][2];
#pragma unroll
    for (int i = 0; i < 8; i++)
#pragma unroll
        for (int j = 0; j < 2; j++) acc[i][j] = (f32x4){0.f, 0.f, 0.f, 0.f};

    const size_t abase = (size_t)b * 4096 + n0;

    for (int kc = 0; kc < 256; kc += 32) {
        s16x8 wh[2], wl[2];
#pragma unroll
        for (int ot = 0; ot < 2; ot++) {
            size_t woff = (size_t)(wv * 32 + ot * 16 + lc) * 256 + kc + lg * 8;
            wh[ot] = *(const s16x8*)(wHs + woff);
            if (MODE != 2) wl[ot] = *(const s16x8*)(wLs + woff);
        }
#pragma unroll
        for (int mt = 0; mt < 8; mt++) {
            size_t aoff = (abase + mt * 16 + lc) * 256 + kc + lg * 8;
            s16x8 ah = *(const s16x8*)(xtH + aoff);
            s16x8 al;
            if (MODE != 2) al = *(const s16x8*)(xtL + aoff);
#pragma unroll
            for (int ot = 0; ot < 2; ot++) {
                acc[mt][ot] = __builtin_amdgcn_mfma_f32_16x16x32_bf16(ah, wh[ot], acc[mt][ot], 0, 0, 0);
                if (MODE != 2) {
                    acc[mt][ot] = __builtin_amdgcn_mfma_f32_16x16x32_bf16(ah, wl[ot], acc[mt][ot], 0, 0, 0);
                    acc[mt][ot] = __builtin_amdgcn_mfma_f32_16x16x32_bf16(al, wh[ot], acc[mt][ot], 0, 0, 0);
                }
            }
        }
    }

    if (MODE == 0) {
#pragma unroll
        for (int mt = 0; mt < 8; mt++)
#pragma unroll
            for (int ot = 0; ot < 2; ot++) {
                int o = wv * 32 + ot * 16 + lc;
                float bs = bias[o];
#pragma unroll
                for (int r = 0; r < 4; r++) {
                    int n = n0 + mt * 16 + lg * 4 + r;
                    float v = acc[mt][ot][r] + bs;
                    unsigned short h = bf16_rne(v);
                    size_t idx = ((size_t)b * 4096 + n) * 128 + o;
                    outH[idx] = h;
                    outL[idx] = bf16_rne(v - bf16_to_f32(h));
                }
            }
    } else {
        const int mbase = blockIdx.x * 32;
#pragma unroll
        for (int mt = 0; mt < 4; mt++)
#pragma unroll
            for (int ot = 0; ot < 2; ot++) {
                int o = wv * 32 + ot * 16 + lc;
                float bs = bias[o];
#pragma unroll
                for (int pair = 0; pair < 2; pair++) {
                    float v = fmaxf(fmaxf(acc[mt][ot][2 * pair], acc[mt][ot][2 * pair + 1]),
                                    fmaxf(acc[mt + 4][ot][2 * pair], acc[mt + 4][ot][2 * pair + 1])) + bs;
                    int pw = mt * 8 + lg * 2 + pair;
                    int m  = mbase + pw;
                    if (MODE == 1) {
                        unsigned short h = bf16_rne(v);
                        size_t idx = ((size_t)b * 1024 + m) * 128 + o;
                        outH[idx] = h;
                        outL[idx] = bf16_rne(v - bf16_to_f32(h));
                    } else {
                        outH[((size_t)b * 128 + o) * 1024 + m] = bf16_rne(v);
                    }
                }
            }
    }
}

// ---------------------------------------------------------------------------
// Flash attention v6 (unchanged from round 8): swapped QK^T, lane-local
// softmax, packed P, XCD batch swizzle, 37 KB LDS, 4 blocks/CU.
// ---------------------------------------------------------------------------
__global__ __launch_bounds__(256, 4) void attn_kernel(
    const unsigned short* __restrict__ thH,  // [16][4096][128]
    const unsigned short* __restrict__ thL,
    const unsigned short* __restrict__ phH,  // [16][1024][128]
    const unsigned short* __restrict__ phL,
    const unsigned short* __restrict__ gp,   // [16][128][1024]  (V^T)
    unsigned short* __restrict__ y)          // [16][4096][128]
{
    const int fid  = blockIdx.x + (blockIdx.y << 6);   // grid (64,16) -> 0..1023
    const int xcd  = fid & 7;
    const int slot = fid >> 3;                          // 0..127
    const int b    = 2 * xcd + (slot >> 6);
    const int n0   = (slot & 63) * 64;

    const int tid = threadIdx.x;
    const int wv  = tid >> 6;
    const int l   = tid & 63;
    const int lg  = l >> 4;
    const int lc  = l & 15;

    __shared__ __align__(16) unsigned short Kh[2][32 * 128];  // 16 KB
    __shared__ __align__(16) unsigned short Kl[2][32 * 128];  // 16 KB
    __shared__ __align__(16) unsigned short Pb[4][16 * 40];   //  5 KB

    const unsigned short* phHb = phH + (size_t)b * 1024 * 128;
    const unsigned short* phLb = phL + (size_t)b * 1024 * 128;
    const unsigned short* gpb  = gp  + (size_t)b * 128 * 1024;
    unsigned short* Pw = Pb[wv];

    s16x8 qh[4], ql[4];
    {
        const size_t qrow = ((size_t)b * 4096 + n0 + wv * 16 + lc) * 128;
#pragma unroll
        for (int ks = 0; ks < 4; ks++) {
            qh[ks] = *(const s16x8*)(thH + qrow + ks * 32 + lg * 8);
            ql[ks] = *(const s16x8*)(thL + qrow + ks * 32 + lg * 8);
        }
    }

    f32x4 O[8];
#pragma unroll
    for (int t = 0; t < 8; t++) O[t] = (f32x4){0.f, 0.f, 0.f, 0.f};
    float mrun = -1e30f;
    float lrun = 0.f;

    const int lr  = l >> 4;
    const int sc_ = l & 15;

#define STAGE(buf, kt_)                                                              \
    {                                                                                \
        _Pragma("unroll")                                                            \
        for (int t = 0; t < 2; t++) {                                                \
            int Rt = wv * 8 + t * 4;                                                 \
            int R  = Rt + lr;                                                        \
            int ck = sc_ ^ (R & 15);                                                 \
            size_t src = ((size_t)((kt_) * 32 + R)) * 128 + ck * 8;                  \
            async_copy16(&Kh[buf][Rt * 128], phHb + src);                            \
            async_copy16(&Kl[buf][Rt * 128], phLb + src);                            \
        }                                                                            \
    }

    STAGE(0, 0);

    for (int kt = 0; kt < 32; kt++) {
        const int cur = kt & 1;
        __syncthreads();
        if (kt < 31) STAGE(cur ^ 1, kt + 1);

        const unsigned short* KhT = Kh[cur];
        const unsigned short* KlT = Kl[cur];

        f32x4 s[2];
#pragma unroll
        for (int ct = 0; ct < 2; ct++) s[ct] = (f32x4){0.f, 0.f, 0.f, 0.f};
#pragma unroll
        for (int ct = 0; ct < 2; ct++) {
            const int row = ct * 16 + lc;
#pragma unroll
            for (int ks = 0; ks < 4; ks++) {
                const int slt = (ks * 4 + lg) ^ lc;
                s16x8 kh = *(const s16x8*)(KhT + row * 128 + slt * 8);
                s16x8 kl = *(const s16x8*)(KlT + row * 128 + slt * 8);
                s[ct] = __builtin_amdgcn_mfma_f32_16x16x32_bf16(kh, qh[ks], s[ct], 0, 0, 0);
                s[ct] = __builtin_amdgcn_mfma_f32_16x16x32_bf16(kl, qh[ks], s[ct], 0, 0, 0);
                s[ct] = __builtin_amdgcn_mfma_f32_16x16x32_bf16(kh, ql[ks], s[ct], 0, 0, 0);
            }
        }

        float tm = fmaxf(fmaxf(fmaxf(s[0][0], s[0][1]), fmaxf(s[0][2], s[0][3])),
                         fmaxf(fmaxf(s[1][0], s[1][1]), fmaxf(s[1][2], s[1][3])));
        tm = fmaxf(tm, __shfl_xor(tm, 16, 64));
        tm = fmaxf(tm, __shfl_xor(tm, 32, 64));

        if (__any(tm > mrun)) {
            float mn  = fmaxf(mrun, tm);
            float scr = __expf(mrun - mn);
            mrun = mn;
            lrun *= scr;
            float scO[4];
#pragma unroll
            for (int r = 0; r < 4; r++) scO[r] = __shfl(scr, lg * 4 + r, 64);
#pragma unroll
            for (int t = 0; t < 8; t++)
#pragma unroll
                for (int r = 0; r < 4; r++) O[t][r] *= scO[r];
        }

        float ts = 0.f;
        float p[8];
#pragma unroll
        for (int ct = 0; ct < 2; ct++)
#pragma unroll
            for (int r = 0; r < 4; r++) {
                float e = __expf(s[ct][r] - mrun);
                p[ct * 4 + r] = e;
                ts += e;
            }
        ts += __shfl_xor(ts, 16, 64);
        ts += __shfl_xor(ts, 32, 64);
        lrun += ts;

#pragma unroll
        for (int ct = 0; ct < 2; ct++) {
            unsigned w0 = (unsigned)bf16_rne(p[ct * 4 + 0]) | ((unsigned)bf16_rne(p[ct * 4 + 1]) << 16);
            unsigned w1 = (unsigned)bf16_rne(p[ct * 4 + 2]) | ((unsigned)bf16_rne(p[ct * 4 + 3]) << 16);
            uint2 pk; pk.x = w0; pk.y = w1;
            *(uint2*)&Pw[lc * 40 + ct * 16 + lg * 4] = pk;
        }

        const int mt = kt * 32;
        s16x8 pa = *(const s16x8*)(Pw + lc * 40 + lg * 8);
#pragma unroll
        for (int ci_t = 0; ci_t < 8; ci_t++) {
            s16x8 vb = *(const s16x8*)(gpb + (size_t)(ci_t * 16 + lc) * 1024 + mt + lg * 8);
            O[ci_t] = __builtin_amdgcn_mfma_f32_16x16x32_bf16(pa, vb, O[ci_t], 0, 0, 0);
        }
    }

    float invO[4];
#pragma unroll
    for (int r = 0; r < 4; r++) {
        float lr_ = __shfl(lrun, lg * 4 + r, 64);
        invO[r] = 1.0f / lr_;
    }
#pragma unroll
    for (int r = 0; r < 4; r++) {
        int n = n0 + wv * 16 + lg * 4 + r;
        size_t base = ((size_t)b * 4096 + n) * 128;
#pragma unroll
        for (int ci_t = 0; ci_t < 8; ci_t++)
            y[base + ci_t * 16 + lc] = bf16_rne(O[ci_t][r] * invO[r]);
    }
#undef STAGE
}

// ---------------------------------------------------------------------------
// W conv: W_y[b][o][n] = sum_ci wbf[o][ci] * y[b][n][ci] + W_b[o]  (bf16 out)
// Weights pre-split (wbf) -> zero conversion VALU.
// ---------------------------------------------------------------------------
__global__ __launch_bounds__(256) void wconv_kernel(
    const unsigned short* __restrict__ y,    // [16][4096][128]
    const unsigned short* __restrict__ wbf,  // [256][128] bf16
    const float* __restrict__ Wb,            // [256]
    unsigned short* __restrict__ wy)         // [16][256][4096]
{
    const int b   = blockIdx.z;
    const int o0  = blockIdx.x * 64;
    const int nb  = blockIdx.y * 256;
    const int tid = threadIdx.x;
    const int wv  = tid >> 6;
    const int l   = tid & 63;
    const int lg  = l >> 4;
    const int lc  = l & 15;
    const int n0  = nb + wv * 64;

    f32x4 acc[4][4];
#pragma unroll
    for (int i = 0; i < 4; i++)
#pragma unroll
        for (int j = 0; j < 4; j++) acc[i][j] = (f32x4){0.f, 0.f, 0.f, 0.f};

#pragma unroll
    for (int ks = 0; ks < 4; ks++) {
        s16x8 a[4];
#pragma unroll
        for (int ot = 0; ot < 4; ot++)
            a[ot] = *(const s16x8*)(wbf + (size_t)(o0 + ot * 16 + lc) * 128 + ks * 32 + lg * 8);
#pragma unroll
        for (int nt = 0; nt < 4; nt++) {
            s16x8 bf = *(const s16x8*)(y + ((size_t)b * 4096 + n0 + nt * 16 + lc) * 128 + ks * 32 + lg * 8);
#pragma unroll
            for (int ot = 0; ot < 4; ot++)
                acc[ot][nt] = __builtin_amdgcn_mfma_f32_16x16x32_bf16(a[ot], bf, acc[ot][nt], 0, 0, 0);
        }
    }
#pragma unroll
    for (int ot = 0; ot < 4; ot++) {
#pragma unroll
        for (int r = 0; r < 4; r++) {
            int o = o0 + ot * 16 + lg * 4 + r;
            float bsv = Wb[o];
#pragma unroll
            for (int nt = 0; nt < 4; nt++) {
                float v = acc[ot][nt][r] + bsv;
                wy[((size_t)b * 256 + o) * 4096 + n0 + nt * 16 + lc] = bf16_rne(v);
            }
        }
    }
}

// ---------------------------------------------------------------------------
__global__ __launch_bounds__(256) void stats_kernel(
    const unsigned short* __restrict__ wy,  // [16][256][4096]
    const float* __restrict__ gamma, const float* __restrict__ beta,
    float* __restrict__ scale, float* __restrict__ shift)
{
    const int o = blockIdx.x;
    const int t = threadIdx.x;
    float s1 = 0.f, s2 = 0.f;
    for (int b = 0; b < 16; b++) {
        const unsigned short* p = wy + ((size_t)b * 256 + o) * 4096;
#pragma unroll
        for (int i = 0; i < 4; i++) {
            uint2 u = *(const uint2*)(p + i * 1024 + t * 4);
            float v0 = bf16_to_f32((unsigned short)(u.x & 0xffff));
            float v1 = bf16_to_f32((unsigned short)(u.x >> 16));
            float v2 = bf16_to_f32((unsigned short)(u.y & 0xffff));
            float v3 = bf16_to_f32((unsigned short)(u.y >> 16));
            s1 += v0 + v1 + v2 + v3;
            s2 += v0 * v0 + v1 * v1 + v2 * v2 + v3 * v3;
        }
    }
#pragma unroll
    for (int d = 1; d < 64; d <<= 1) { s1 += __shfl_xor(s1, d, 64); s2 += __shfl_xor(s2, d, 64); }
    __shared__ float rs1[4], rs2[4];
    if ((t & 63) == 0) { rs1[t >> 6] = s1; rs2[t >> 6] = s2; }
    __syncthreads();
    if (t == 0) {
        float S1 = rs1[0] + rs1[1] + rs1[2] + rs1[3];
        float S2 = rs2[0] + rs2[1] + rs2[2] + rs2[3];
        const float cnt = 16.0f * 4096.0f;
        float mean = S1 / cnt;
        float var  = S2 / cnt - mean * mean;
        float sc = gamma[o] * rsqrtf(var + 1e-5f);
        scale[o] = sc;
        shift[o] = beta[o] - mean * sc;
    }
}

// ---------------------------------------------------------------------------
__global__ __launch_bounds__(256) void final_kernel(
    const unsigned short* __restrict__ wy,
    const float* __restrict__ x,
    const float* __restrict__ scale, const float* __restrict__ shift,
    const float* __restrict__ inp0,
    float* __restrict__ out)
{
    if (blockIdx.x == 0 && threadIdx.x == 0) out[0] = inp0[0];
    float* z = out + 1;
    const size_t total4 = (size_t)16 * 256 * 4096 / 4;
    for (size_t v = (size_t)blockIdx.x * 256 + threadIdx.x; v < total4; v += (size_t)gridDim.x * 256) {
        size_t e = v * 4;
        int c = (int)((e >> 12) & 255);
        uint2 u = *(const uint2*)(wy + e);
        float4 xv = *(const float4*)(x + e);
        float sc = scale[c], sh = shift[c];
        float z0 = sc * bf16_to_f32((unsigned short)(u.x & 0xffff)) + sh + xv.x;
        float z1 = sc * bf16_to_f32((unsigned short)(u.x >> 16))    + sh + xv.y;
        float z2 = sc * bf16_to_f32((unsigned short)(u.y & 0xffff)) + sh + xv.z;
        float z3 = sc * bf16_to_f32((unsigned short)(u.y >> 16))    + sh + xv.w;
        z[e + 0] = z0; z[e + 1] = z1; z[e + 2] = z2; z[e + 3] = z3;
    }
}

// ---------------------------------------------------------------------------
extern "C" void kernel_launch(void* const* d_in, const int* in_sizes, int n_in,
                              void* d_out, int out_size, void* d_ws, size_t ws_size,
                              hipStream_t stream) {
    const float* inp0  = (const float*)d_in[0];
    const float* x     = (const float*)d_in[1];
    const float* g_w   = (const float*)d_in[2];
    const float* g_b   = (const float*)d_in[3];
    const float* th_w  = (const float*)d_in[4];
    const float* th_b  = (const float*)d_in[5];
    const float* ph_w  = (const float*)d_in[6];
    const float* ph_b  = (const float*)d_in[7];
    const float* W_w   = (const float*)d_in[8];
    const float* W_b   = (const float*)d_in[9];
    const float* gamma = (const float*)d_in[10];
    const float* beta  = (const float*)d_in[11];

    char* ws = (char*)d_ws;
    const size_t MB = 1048576;
    // Timeline-aliased layout (peak ~111 MB):
    unsigned short* xtH = (unsigned short*)(ws);                  // 32 MB (dead after convs)
    unsigned short* xtL = (unsigned short*)(ws + 32 * MB);        // 32 MB (dead after convs)
    unsigned short* thH = (unsigned short*)(ws + 64 * MB);        // 16 MB
    unsigned short* thL = (unsigned short*)(ws + 80 * MB);        // 16 MB
    unsigned short* phH = (unsigned short*)(ws + 96 * MB);        // 4 MB
    unsigned short* phL = (unsigned short*)(ws + 100 * MB);       // 4 MB
    unsigned short* gpv = (unsigned short*)(ws + 104 * MB);       // 4 MB
    unsigned short* wHs = (unsigned short*)(ws + 108 * MB);       // 192 KB
    unsigned short* wLs = (unsigned short*)(ws + 109 * MB);       // 192 KB
    unsigned short* wbf = (unsigned short*)(ws + 110 * MB);       // 64 KB
    float* scaleb       = (float*)(ws + 111 * MB);                // 1 KB
    float* shiftb       = (float*)(ws + 111 * MB + 4096);         // 1 KB
    unsigned short* yv  = (unsigned short*)(ws + 32 * MB);        // alias xtL (16 MB)
    unsigned short* wy  = (unsigned short*)(ws);                  // alias xtH (32 MB)

    wsplit_kernel<<<dim3(512), 256, 0, stream>>>(th_w, ph_w, g_w, W_w, wHs, wLs, wbf);
    xsplit_kernel<<<dim3(32, 16), 256, 0, stream>>>(x, xtH, xtL);
    conv_kernel<0><<<dim3(32, 16), 256, 0, stream>>>(xtH, xtL, wHs,         wLs,         th_b, thH, thL);
    conv_kernel<1><<<dim3(32, 16), 256, 0, stream>>>(xtH, xtL, wHs + 32768, wLs + 32768, ph_b, phH, phL);
    conv_kernel<2><<<dim3(32, 16), 256, 0, stream>>>(xtH, xtL, wHs + 65536, wHs + 65536, g_b,  gpv, gpv);
    attn_kernel<<<dim3(64, 16), 256, 0, stream>>>(thH, thL, phH, phL, gpv, yv);
    wconv_kernel<<<dim3(4, 16, 16), 256, 0, stream>>>(yv, wbf, W_b, wy);
    stats_kernel<<<dim3(256), 256, 0, stream>>>(wy, gamma, beta, scaleb, shiftb);
    final_kernel<<<dim3(2048), 256, 0, stream>>>(wy, x, scaleb, shiftb, inp0, (float*)d_out);
}